// Round 8
// baseline (87.820 us; speedup 1.0000x reference)
//
#include <hip/hip_runtime.h>
#include <math.h>

// Problem constants
// B=16, O=24, V=2, P0=32, P1=64, P2=64, R=3, C=16, UI=1, BI=2
// NUM_IN = 288 (72 chunks of 4), P = 552 perms (p = a*23 + j, bb = j + (j>=a))
// in_tensor per (b,p): [nullary(32) | unary[a](64) | unary[bb](64) |
//                       binary[a][j](64) | binary[bb][a-(a>bb)](64)]
// out: [nullary_out(16) | unary_out(16*24) | binary_out(16*24*23)]

#define XST 290   // xs row stride in floats (288 + 2 pad)

__device__ __forceinline__ float sigm(float x) { return 1.0f / (1.0f + expf(-x)); }

// ---------------- Kernel 1: softmax prep ----------------
// and_kernel: (3,16,288,3) -> dke layout [ch=i/4][c][r][8]: {d0..d3, e0..e3}
// conj term: x*s0 + (1-x)*s1 + s2 = fma(x, s0-s1, s1+s2) = fma(x, d, e)
__global__ __launch_bounds__(256) void prep_kernel(const float* __restrict__ ak,
                                                   const float* __restrict__ temp,
                                                   float* __restrict__ dke) {
    int idx = blockIdx.x * 256 + threadIdx.x;   // (r,c,i) over 3*16*288
    if (idx >= 3 * 16 * 288) return;
    int i = idx % 288;
    int c = (idx / 288) % 16;
    int r = idx / (16 * 288);
    float invT = 1.0f / temp[0];
    const float* p = ak + (size_t)idx * 3;
    float a0 = p[0] * invT, a1 = p[1] * invT, a2 = p[2] * invT;
    float mx = fmaxf(a0, fmaxf(a1, a2));
    float e0 = expf(a0 - mx), e1 = expf(a1 - mx), e2 = expf(a2 - mx);
    float inv = 1.0f / (e0 + e1 + e2);
    float s0 = e0 * inv, s1 = e1 * inv, s2 = e2 * inv;
    int ch = i >> 2, lane = i & 3;
    float* q = dke + (((size_t)(ch * 16 + c) * 3 + r) * 8) + lane;
    q[0] = s0 - s1;   // d
    q[4] = s1 + s2;   // e
}

// ---------------- Kernel 2: fused conjuncts + combine, 2 a-values/block ----------------
// grid: 16*12 = 192 blocks (b, apair) -> single round on 256 CUs, 4 waves/SIMD.
// block: 1024 threads = half(2) x [iq(8) x pl(4) x c(16)]. a = apair*2 + half.
// Thread: 6 perms j = pl + 4m (m=0..5; j==23 pad) x 9 chunks [iq*9, iq*9+9).
__global__ __launch_bounds__(1024, 4) void mega_kernel(const float* __restrict__ nullary,
                                                       const float* __restrict__ unary,
                                                       const float* __restrict__ binary,
                                                       const float* __restrict__ dke,
                                                       const float* __restrict__ orK,
                                                       const float* __restrict__ temp,
                                                       float* __restrict__ out,
                                                       float* __restrict__ ws0) {
    __shared__ float xs[2][24 * XST];      // 55.7 KB
    __shared__ float part[2][7][64][18];   // 64.5 KB  (total 117 KB, 1 block/CU)

    const int tid = threadIdx.x;
    const int half = tid >> 9;
    const int t9 = tid & 511;
    const int b = blockIdx.x / 12;
    const int a = (blockIdx.x % 12) * 2 + half;

    // ---- stage x for 24 perms (23 real + 1 pad), all 72 chunks ----
    for (int idx = t9; idx < 24 * 72; idx += 512) {
        int perm = idx / 72;
        int gc = idx % 72;
        int je = perm < 23 ? perm : 22;     // pad perm = copy of j=22
        int bb = je + (je >= a ? 1 : 0);
        int aadj = (a > bb) ? (a - 1) : a;
        const float* src;
        if (gc < 8)        src = nullary + b * 32 + gc * 4;
        else if (gc < 24)  src = unary + ((size_t)b * 24 + a) * 64 + (gc - 8) * 4;
        else if (gc < 40)  src = unary + ((size_t)b * 24 + bb) * 64 + (gc - 24) * 4;
        else if (gc < 56)  src = binary + (((size_t)b * 24 + a) * 23 + je) * 64 + (gc - 40) * 4;
        else               src = binary + (((size_t)b * 24 + bb) * 23 + aadj) * 64 + (gc - 56) * 4;
        float4 v = *(const float4*)src;
        *(float4*)&xs[half][perm * XST + gc * 4] = v;
    }
    __syncthreads();

    const int iq = t9 >> 6;          // 0..7 : 9-chunk segment (one wave per iq per half)
    const int pl = (t9 >> 4) & 3;    // 0..3
    const int c  = t9 & 15;          // 0..15

    float acc[6][3];
#pragma unroll
    for (int m = 0; m < 6; ++m)
#pragma unroll
        for (int r = 0; r < 3; ++r) acc[m][r] = 1.0f;

    const int lc0 = iq * 9;
#pragma unroll 3
    for (int lc = lc0; lc < lc0 + 9; ++lc) {
        float4 xv[6];
#pragma unroll
        for (int m = 0; m < 6; ++m)
            xv[m] = *(const float4*)&xs[half][(pl + 4 * m) * XST + lc * 4];
        const float* kp = dke + (size_t)(lc * 16 + c) * 24;
#pragma unroll
        for (int r = 0; r < 3; ++r) {
            float4 d = *(const float4*)(kp + r * 8);
            float4 e = *(const float4*)(kp + r * 8 + 4);
#pragma unroll
            for (int m = 0; m < 6; ++m) {
                float t0 = fmaf(xv[m].x, d.x, e.x);
                float t1 = fmaf(xv[m].y, d.y, e.y);
                float t2 = fmaf(xv[m].z, d.z, e.z);
                float t3 = fmaf(xv[m].w, d.w, e.w);
                acc[m][r] *= (t0 * t1) * (t2 * t3);
            }
        }
    }

    // ---- combine the 8 iq slices (per half) ----
    if (iq >= 1) {
        float* p = part[half][iq - 1][pl * 16 + c];
#pragma unroll
        for (int m = 0; m < 6; ++m)
#pragma unroll
            for (int r = 0; r < 3; ++r) p[m * 3 + r] = acc[m][r];
    }
    __syncthreads();

    if (iq == 0) {
        const int row = pl * 16 + c;   // == t9 (0..63): wave 0 of this half
#pragma unroll
        for (int s = 0; s < 7; ++s)
#pragma unroll
            for (int m = 0; m < 6; ++m)
#pragma unroll
                for (int r = 0; r < 3; ++r)
                    acc[m][r] *= part[half][s][row][m * 3 + r];

        const float T = temp[0];
        const float ok2 = sigm(orK[32 + c] / T);

        // binary: out[b,a,j] = 1 - prod_c(1 - conj2 * ok2[c]); j = pl + 4m
#pragma unroll
        for (int m = 0; m < 6; ++m) {
            int j = pl + 4 * m;
            float w = 1.0f - acc[m][2] * ok2;
#pragma unroll
            for (int off = 1; off < 16; off <<= 1) w *= __shfl_xor(w, off, 16);
            if (c == 0 && j < 23) out[400 + ((size_t)b * 24 + a) * 23 + j] = 1.0f - w;
        }

        // unary + nullary: product over this thread's perms, then across pl
        float u1 = 1.0f, u0 = 1.0f;
#pragma unroll
        for (int m = 0; m < 6; ++m) {
            int j = pl + 4 * m;
            if (j < 23) {
                u1 *= (1.0f - acc[m][1]);
                u0 *= (1.0f - acc[m][0]);
            }
        }
        u1 *= __shfl_xor(u1, 16, 64);  u1 *= __shfl_xor(u1, 32, 64);
        u0 *= __shfl_xor(u0, 16, 64);  u0 *= __shfl_xor(u0, 32, 64);

        // unary out
        {
            float ok1 = sigm(orK[16 + c] / T);
            float w = 1.0f - (1.0f - u1) * ok1;
#pragma unroll
            for (int off = 1; off < 16; off <<= 1) w *= __shfl_xor(w, off, 16);
            if (t9 == 0) out[16 + (size_t)b * 24 + a] = 1.0f - w;
        }
        // nullary partial
        if (pl == 0) ws0[((size_t)b * 24 + a) * 16 + c] = u0;
    }
}

// ---------------- Kernel 3: nullary finish ----------------
__global__ __launch_bounds__(256) void final_kernel(const float* __restrict__ ws0,
                                                    const float* __restrict__ orK,
                                                    const float* __restrict__ temp,
                                                    float* __restrict__ out) {
    int tid = threadIdx.x;       // 256 = 16 b * 16 c
    int b = tid >> 4, c = tid & 15;
    float p = 1.0f;
#pragma unroll
    for (int a = 0; a < 24; ++a) p *= ws0[((size_t)b * 24 + a) * 16 + c];
    float T = temp[0];
    float ok0 = sigm(orK[c] / T);
    float w = 1.0f - (1.0f - p) * ok0;
#pragma unroll
    for (int off = 1; off < 16; off <<= 1) w *= __shfl_xor(w, off, 16);
    if (c == 0) out[b] = 1.0f - w;
}

extern "C" void kernel_launch(void* const* d_in, const int* in_sizes, int n_in,
                              void* d_out, int out_size, void* d_ws, size_t ws_size,
                              hipStream_t stream) {
    const float* nullary = (const float*)d_in[0];   // (16,32)
    const float* unary   = (const float*)d_in[1];   // (16,24,64)
    const float* binary  = (const float*)d_in[2];   // (16,24,23,64)
    const float* ak      = (const float*)d_in[3];   // (3,16,288,3)
    const float* orK     = (const float*)d_in[4];   // (3,16)
    const float* temp    = (const float*)d_in[5];   // scalar

    float* out = (float*)d_out;                     // 16 + 384 + 8832 floats
    float* dke = (float*)d_ws;                      // 72*16*3*8 = 27648 floats
    float* ws0 = dke + 27648;                       // 16*24*16 = 6144 floats

    prep_kernel<<<54, 256, 0, stream>>>(ak, temp, dke);
    mega_kernel<<<16 * 12, 1024, 0, stream>>>(nullary, unary, binary, dke, orK, temp, out, ws0);
    final_kernel<<<1, 256, 0, stream>>>(ws0, orK, temp, out);
}